// Round 12
// baseline (211.698 us; speedup 1.0000x reference)
//
#include <hip/hip_runtime.h>
#include <hip/hip_bf16.h>
#include <cstdint>
#include <cstddef>

#define BATCH 4096
#define INC   1024
#define OUTC  1024
#define NB    8
#define KDIM  (INC * NB)   // 8192 (elements == bytes in i8)

// GEMM: 256x256 tile, 8 waves (2M x 4N), wave tile 128x64 (8x4 frags of
// 16x16x64 i8). R12: BARRIER-FREE. All six prior variants (38-42 us, MfmaUtil
// ~30%) shared LDS tiles -> per-step block barriers -> LDS pipe (~1500 cyc/step)
// and MFMA pipe (~1300) run alternately. Here each wave loads its MFMA
// fragments DIRECTLY from global (L2-resident i8: per-XCD working set ~2.5 MB
// with bx-minor ordering): lane pattern {l,l+16,l+32,l+48} covers 64 contiguous
// bytes -> 16x64B segments per dwordx4. No LDS, no barriers, no inline asm in
// the loop; compiler emits per-register counted vmcnt; waves free-run so load
// latency hides under other waves' MFMA (m114 TLP). Double-buffered operand
// register sets (named, rule #20). Packed-coalesced partial epilogue (R7/R8,
// verified) + unchanged reduce kernel.
#define BM 256
#define BN 256
#define BKB 64                  // k-bytes per step
#define SPLITS 4
#define KZ (KDIM / SPLITS)      // 2048 bytes per z
#define KSTEPS (KZ / BKB)       // 32 even steps
#define GRID_BLOCKS ((OUTC / BN) * (BATCH / BM) * SPLITS)   // 4*16*4 = 256 = 1 block/CU

// prep dispatch partition: expand | fused rowmax+quant (one block per coeff row)
#define EXPAND_BLOCKS  ((BATCH * INC) / 256)   // 16384
#define QUANT_BLOCKS   OUTC                    // 1024
#define PREP_BLOCKS    (EXPAND_BLOCKS + QUANT_BLOCKS)

typedef int      v4i __attribute__((ext_vector_type(4)));
typedef unsigned v4u __attribute__((ext_vector_type(4)));
typedef char     v8c __attribute__((ext_vector_type(8)));

__device__ __forceinline__ unsigned short f2bf(float f) {
  union { float f; unsigned u; } v; v.f = f;
  unsigned r = v.u + 0x7fffu + ((v.u >> 16) & 1u);  // round-to-nearest-even
  return (unsigned short)(r >> 16);
}
__device__ __forceinline__ float bf2f(unsigned short h) {
  union { unsigned u; float f; } v; v.u = ((unsigned)h) << 16; return v.f;
}

// ---------------- Phase 1 (fused dispatch): expand basis | rowmax+quantize coeffs -------
__global__ __launch_bounds__(256) void prep_kernel(
    const float* __restrict__ x, const float4* __restrict__ coeffs4,
    const float* __restrict__ centers, const float* __restrict__ slopes,
    const float* __restrict__ alpha, const float* __restrict__ beta,
    char* __restrict__ Ai8, int* __restrict__ Ci8i,
    float* __restrict__ maxrow, int* __restrict__ qcsum) {
  const int blk = blockIdx.x;
  const int tid = threadIdx.x;
  if (blk < EXPAND_BLOCKS) {
    const int idx = blk * 256 + tid;          // (b,i) pair
    const int i = idx & (INC - 1);
    const float u = alpha[i] * x[idx] + beta[i];
    const float s0 = slopes[i * NB];
    const float c0 = centers[i * NB];
    const float c1 = centers[i * NB + 1];
    const float L2E2 = 2.8853900817779268f;   // 2*log2(e)
    const float a2 = L2E2 * s0;
    float e = __builtin_amdgcn_exp2f(a2 * (c0 - u));   // inf -> rcp -> 0: correct limit
    const float R = __builtin_amdgcn_exp2f(a2 * (c1 - c0));
    v8c q;
#pragma unroll
    for (int m = 0; m < 8; ++m) {
      float basis = __builtin_amdgcn_rcpf(1.0f + e);
      q[m] = (char)(int)rintf(basis * 254.0f - 127.0f);
      e *= R;
    }
    *(v8c*)(Ai8 + (size_t)idx * 8) = q;   // 8B coalesced store
  } else {
    const int o = blk - EXPAND_BLOCKS;
    const float4* row = coeffs4 + (size_t)o * (KDIM / 4);
    float4 v[8];
    float m = 0.0f;
#pragma unroll
    for (int j = 0; j < 8; ++j) {
      v[j] = row[tid + 256 * j];
      m = fmaxf(m, fmaxf(fmaxf(fabsf(v[j].x), fabsf(v[j].y)),
                         fmaxf(fabsf(v[j].z), fabsf(v[j].w))));
    }
#pragma unroll
    for (int off = 32; off; off >>= 1) m = fmaxf(m, __shfl_xor(m, off));
    __shared__ float wm_[4];
    __shared__ int   wq_[4];
    if ((tid & 63) == 0) wm_[tid >> 6] = m;
    __syncthreads();
    const float M = fmaxf(fmaxf(fmaxf(wm_[0], wm_[1]), fmaxf(wm_[2], wm_[3])), 1e-30f);
    const float s = 127.0f / M;
    int qs = 0;
#pragma unroll
    for (int j = 0; j < 8; ++j) {
      int q0 = (int)rintf(v[j].x * s), q1 = (int)rintf(v[j].y * s);
      int q2 = (int)rintf(v[j].z * s), q3 = (int)rintf(v[j].w * s);
      Ci8i[(size_t)o * (KDIM / 4) + tid + 256 * j] =
          (q0 & 0xFF) | ((q1 & 0xFF) << 8) | ((q2 & 0xFF) << 16) | ((q3 & 0xFF) << 24);
      qs += q0 + q1 + q2 + q3;
    }
#pragma unroll
    for (int off = 32; off; off >>= 1) qs += __shfl_xor(qs, off);
    if ((tid & 63) == 0) wq_[tid >> 6] = qs;
    __syncthreads();
    if (tid == 0) { maxrow[o] = M; qcsum[o] = wq_[0] + wq_[1] + wq_[2] + wq_[3]; }
  }
}

// ---------------- Phase 2: i8 16x16x64 MFMA GEMM, barrier-free direct-operand -----------
// Fragment addressing (same data as the verified LDS path end-to-end):
//   a[f] lane l = 16B at A[(bm0 + wm + f*16 + (l&15)) * KDIM + kt0 + t*64 + (l>>4)*16]
//   b[f] lane l = 16B at C[(bn0 + wn + f*16 + (l&15)) * KDIM + kt0 + t*64 + (l>>4)*16]
// Lanes {l, l+16, l+32, l+48} read 64 contiguous bytes of one row.
// Block ordering within a z-plane: bx minor -> 4 consecutive blocks share one
// 512 KB A panel and stream the same 2 MB B -> per-XCD L2 working set ~2.5 MB.
__global__ __launch_bounds__(512, 2) void gemm_kernel(
    const char* __restrict__ A, const char* __restrict__ C,
    unsigned* __restrict__ partials) {
  // XCD-aware bijective remap: each XCD owns 32 consecutive logical blocks
  const int id = (blockIdx.x & 7) * (GRID_BLOCKS / 8) + (blockIdx.x >> 3);
  const int z  = id >> 6;          // 64 blocks per z-plane
  const int p  = id & 63;
  const int by = p >> 2;           // 16 M-tiles
  const int bx = p & 3;            // 4 N-tiles (minor: A-panel locality)
  const int bm0 = by * BM;
  const int bn0 = bx * BN;
  const int kt0 = z * KZ;

  const int tid  = threadIdx.x;
  const int wave = tid >> 6;
  const int lane = tid & 63;
  const int quad = lane >> 4;
  const int lm   = lane & 15;
  const int wm   = (wave >> 2) * 128;   // 2 M-wave-groups
  const int wn   = (wave & 3) * 64;     // 4 N-wave-groups

  // per-lane fragment base pointers (fragment f at +f*16*KDIM, step t at +t*64)
  const char* aBase = A + (size_t)(bm0 + wm + lm) * KDIM + kt0 + quad * 16;
  const char* bBase = C + (size_t)(bn0 + wn + lm) * KDIM + kt0 + quad * 16;

  v4i acc[8][4] = {};
  v4i xa[8], xb[4], ya[8], yb[4];   // two named operand sets

#define LOADF(AV, BV, T)                                                     \
  {                                                                          \
    _Pragma("unroll")                                                        \
    for (int f = 0; f < 8; ++f)                                              \
      AV[f] = *(const v4i*)(aBase + (size_t)f * (16 * KDIM) + (size_t)(T) * BKB); \
    _Pragma("unroll")                                                        \
    for (int f = 0; f < 4; ++f)                                              \
      BV[f] = *(const v4i*)(bBase + (size_t)f * (16 * KDIM) + (size_t)(T) * BKB); \
  }

#define MFMA32(AV, BV)                                                       \
  {                                                                          \
    _Pragma("unroll")                                                        \
    for (int fm = 0; fm < 8; ++fm)                                           \
      _Pragma("unroll")                                                      \
      for (int fn = 0; fn < 4; ++fn)                                         \
        acc[fm][fn] = __builtin_amdgcn_mfma_i32_16x16x64_i8(AV[fm], BV[fn], acc[fm][fn], 0, 0, 0); \
  }

  // software pipeline: load t+1 while MFMA t; compiler emits counted vmcnt
  LOADF(xa, xb, 0)
  for (int i = 0; i < 15; ++i) {
    const int t = 2 * i;
    LOADF(ya, yb, t + 1)
    MFMA32(xa, xb)
    LOADF(xa, xb, t + 2)
    MFMA32(ya, yb)
  }
  LOADF(ya, yb, 31)
  MFMA32(xa, xb)
  MFMA32(ya, yb)
#undef MFMA32
#undef LOADF

  // ---- packed epilogue: 64 bf16-pair words per lane, 16 coalesced dwordx4 stores ----
  unsigned w32[64];
#pragma unroll
  for (int fm = 0; fm < 8; ++fm)
#pragma unroll
    for (int fn = 0; fn < 4; ++fn)
#pragma unroll
      for (int rr = 0; rr < 2; ++rr)
        w32[fm * 8 + fn * 2 + rr] =
            (unsigned)f2bf((float)acc[fm][fn][2 * rr]) |
            ((unsigned)f2bf((float)acc[fm][fn][2 * rr + 1]) << 16);

  unsigned* outp = partials + (((size_t)z * 64 + p) * 8 + wave) * 4096 + lane * 4;
#pragma unroll
  for (int c = 0; c < 16; ++c)
    *(v4u*)(outp + c * 256) = v4u{w32[4 * c], w32[4 * c + 1], w32[4 * c + 2], w32[4 * c + 3]};
}

// ---------------- Phase 3: reduce + dequant + un-pack transpose ----------------
// One block per (p, w) 128x64 output region; sums 4 z-copies of the packed
// region (fully coalesced dwordx4), decodes (chunk,lane,word)->(b,o), dequants,
// transposes through LDS, writes out [b][o] coalesced. (Verified R8/R11.)
__global__ __launch_bounds__(256) void reduce_kernel(
    const unsigned* __restrict__ P, const float* __restrict__ maxrow,
    const int* __restrict__ qcsum, float* __restrict__ out) {
  const int blk = blockIdx.x;         // 0..511
  const int p = blk >> 3, w = blk & 7;
  const int by = p >> 2, bx = p & 3;
  const int B0 = by * BM + (w >> 2) * 128;
  const int O0 = bx * BN + (w & 3) * 64;
  const int t = threadIdx.x;
  const int l = t & 63;

  __shared__ float tile[128][65];
  __shared__ float sM[64];
  __shared__ float sQ[64];
  if (t < 64) { sM[t] = maxrow[O0 + t]; sQ[t] = 127.0f * (float)qcsum[O0 + t]; }
  __syncthreads();

  const size_t region = ((size_t)p * 8 + w) * 4096;
  const size_t zs     = (size_t)64 * 8 * 4096;   // u32 per z-plane
  float slo[16] = {}, shi[16] = {};
#pragma unroll
  for (int z = 0; z < SPLITS; ++z) {
#pragma unroll
    for (int r = 0; r < 4; ++r) {
      v4u u = *(const v4u*)(P + z * zs + region + ((t >> 6) + r * 4) * 256 + l * 4);
#pragma unroll
      for (int i = 0; i < 4; ++i) {
        slo[r * 4 + i] += bf2f((unsigned short)(u[i] & 0xFFFFu));
        shi[r * 4 + i] += bf2f((unsigned short)(u[i] >> 16));
      }
    }
  }
  const float inv = 1.0f / 32258.0f;   // 127*254
#pragma unroll
  for (int r = 0; r < 4; ++r)
#pragma unroll
    for (int i = 0; i < 4; ++i) {
      const int jj = (t >> 6) * 4 + r * 16 + i;       // fm*8 + fn*2 + rr
      const int fm = jj >> 3, fn = (jj >> 1) & 3, rr = jj & 1;
      const int bl = fm * 16 + (l >> 4) * 4 + rr * 2;
      const int ol = fn * 16 + (l & 15);
      const float M = sM[ol], corr = sQ[ol];
      tile[bl][ol]     = M * (slo[r * 4 + i] + corr) * inv;
      tile[bl + 1][ol] = M * (shi[r * 4 + i] + corr) * inv;
    }
  __syncthreads();

  const int row = t >> 1;
  const int c0  = (t & 1) * 32;
  float* op = out + (size_t)(B0 + row) * OUTC + O0 + c0;
#pragma unroll
  for (int i = 0; i < 8; ++i)
    *(float4*)(op + 4 * i) = float4{tile[row][c0 + 4 * i],     tile[row][c0 + 4 * i + 1],
                                    tile[row][c0 + 4 * i + 2], tile[row][c0 + 4 * i + 3]};
}

extern "C" void kernel_launch(void* const* d_in, const int* in_sizes, int n_in,
                              void* d_out, int out_size, void* d_ws, size_t ws_size,
                              hipStream_t stream) {
  const float* x       = (const float*)d_in[0];
  const float* coeffs  = (const float*)d_in[1];
  const float* centers = (const float*)d_in[2];
  const float* slopes  = (const float*)d_in[3];
  const float* alpha   = (const float*)d_in[4];
  const float* beta    = (const float*)d_in[5];
  float* out = (float*)d_out;

  const size_t a_bytes    = (size_t)BATCH * KDIM;                 // 32 MiB i8
  const size_t c_bytes    = (size_t)OUTC * KDIM;                  // 8 MiB i8
  const size_t stat_bytes = OUTC * sizeof(float);                 // 4 KiB
  const size_t qcs_bytes  = OUTC * sizeof(int);                   // 4 KiB
  const size_t part_bytes = (size_t)SPLITS * BATCH * OUTC * 2;    // 32 MiB bf16-pairs
  if (ws_size < a_bytes + c_bytes + stat_bytes + qcs_bytes + part_bytes) return;

  char*  Ai8    = (char*)d_ws;
  char*  Ci8    = Ai8 + a_bytes;
  float* maxrow = (float*)(Ci8 + c_bytes);
  int*   qcsum  = (int*)((char*)maxrow + stat_bytes);
  unsigned* parts = (unsigned*)((char*)qcsum + qcs_bytes);

  prep_kernel<<<PREP_BLOCKS, 256, 0, stream>>>(
      x, (const float4*)coeffs, centers, slopes, alpha, beta,
      Ai8, (int*)Ci8, maxrow, qcsum);

  gemm_kernel<<<GRID_BLOCKS, 512, 0, stream>>>(Ai8, Ci8, parts);

  reduce_kernel<<<64 * 8, 256, 0, stream>>>(parts, maxrow, qcsum, out);
}